// Round 10
// baseline (108.192 us; speedup 1.0000x reference)
//
#include <hip/hip_runtime.h>
#include <hip/hip_bf16.h>
#include <math.h>

// Problem constants: R,C,D,ORDER = 2048,2048,64,3; O=4
#define R_DIM 2048
#define C_DIM 2048
#define D_DIM 64
// dist^2[r,c] = sum_k A[r,k]*B[c,k] + ||zc||^2
//   k in [0,256):   A = z_rows[o][r][d] (bf16, inline-converted)
//                   B = -2*coef_o(t_c)*z_cols[c][d] (bf16, inline)
//   k in [256,272): A = Gram[r] 4x4 (prep), B = coef outer products (prep)
//   k in [272,288): zero (no loads; zero fragments)

typedef __attribute__((ext_vector_type(8))) short short8;   // bf16x8 MFMA frag
typedef __attribute__((ext_vector_type(4))) float floatx4;  // fp32x4 acc

__device__ __forceinline__ ushort f2bf(float f) {  // RNE float->bf16
  unsigned u = __float_as_uint(f);
  return (ushort)((u + 0x7FFFu + ((u >> 16) & 1u)) >> 16);
}

// pack two float4 -> bf16x8 fragment (RNE, hw packed cvt where available)
__device__ __forceinline__ short8 pack8(float4 a, float4 b) {
  union { short8 s; __hip_bfloat162 h[4]; } u;
  u.h[0] = __float22bfloat162_rn(make_float2(a.x, a.y));
  u.h[1] = __float22bfloat162_rn(make_float2(a.z, a.w));
  u.h[2] = __float22bfloat162_rn(make_float2(b.x, b.y));
  u.h[3] = __float22bfloat162_rn(make_float2(b.z, b.w));
  return u.s;
}
__device__ __forceinline__ float4 scale4(float s, float4 v) {
  float4 r;
  r.x = s * v.x; r.y = s * v.y; r.z = s * v.z; r.w = s * v.w;
  return r;
}

// ---------------- tiny prep: Gram 4x4 (bf16), coef products (bf16), nzc ------
// grid 2048 x 64 (1 wave). Output 128KB + 8KB — no big A/B materialization.
__global__ void prep_kernel(const float* __restrict__ col_times,
                            const float* __restrict__ z_rows,
                            const float* __restrict__ z_cols,
                            ushort* __restrict__ Ag,
                            ushort* __restrict__ Bg,
                            float* __restrict__ nzc) {
  const int r = blockIdx.x;
  const int lane = threadIdx.x;  // 64
  float zv[4];
#pragma unroll
  for (int o = 0; o < 4; ++o)
    zv[o] = z_rows[(size_t)(o * R_DIM + r) * D_DIM + lane];
  float g00 = zv[0] * zv[0], g01 = zv[0] * zv[1], g02 = zv[0] * zv[2],
        g03 = zv[0] * zv[3], g11 = zv[1] * zv[1], g12 = zv[1] * zv[2],
        g13 = zv[1] * zv[3], g22 = zv[2] * zv[2], g23 = zv[2] * zv[3],
        g33 = zv[3] * zv[3];
#pragma unroll
  for (int off = 32; off > 0; off >>= 1) {
    g00 += __shfl_xor(g00, off); g01 += __shfl_xor(g01, off);
    g02 += __shfl_xor(g02, off); g03 += __shfl_xor(g03, off);
    g11 += __shfl_xor(g11, off); g12 += __shfl_xor(g12, off);
    g13 += __shfl_xor(g13, off); g22 += __shfl_xor(g22, off);
    g23 += __shfl_xor(g23, off); g33 += __shfl_xor(g33, off);
  }
  if (lane == 0) {
    ushort* e = Ag + (size_t)r * 16;  // full symmetric 4x4
    e[0] = f2bf(g00);  e[1] = f2bf(g01);  e[2] = f2bf(g02);  e[3] = f2bf(g03);
    e[4] = f2bf(g01);  e[5] = f2bf(g11);  e[6] = f2bf(g12);  e[7] = f2bf(g13);
    e[8] = f2bf(g02);  e[9] = f2bf(g12);  e[10] = f2bf(g22); e[11] = f2bf(g23);
    e[12] = f2bf(g03); e[13] = f2bf(g13); e[14] = f2bf(g23); e[15] = f2bf(g33);
  }
  const float zc = z_cols[(size_t)r * D_DIM + lane];
  float q = zc * zc;
#pragma unroll
  for (int off = 32; off > 0; off >>= 1) q += __shfl_xor(q, off);
  if (lane == 0) nzc[r] = q;
  const float tt = col_times[r];
  float cf[4];
  cf[0] = 1.0f; cf[1] = tt; cf[2] = tt * tt * 0.5f;
  cf[3] = cf[2] * tt * (1.0f / 3.0f);
  if (lane < 16) Bg[(size_t)r * 16 + lane] = f2bf(cf[lane >> 2] * cf[lane & 3]);
}

// ---------------- pair: inline-convert MFMA GEMM, no materialized A/B --------
// 64x64 tile, 4 waves 2x2 (32x32/wave), grid 1024, 4 blocks/CU.
// Fragments built in-register from fp32 z data (L2-resident); events read raw
// in C/D-layout pattern at kernel start + asm-pinned mid-loop.
__launch_bounds__(256, 4)
__global__ void pair_kernel(const int* __restrict__ events,
                            const float* __restrict__ col_times,
                            const float* __restrict__ z_rows,
                            const float* __restrict__ z_cols,
                            const float* __restrict__ gamma_rows,
                            const float* __restrict__ gamma_cols,
                            const ushort* __restrict__ Ag,
                            const ushort* __restrict__ Bg,
                            const float* __restrict__ nzc,
                            float* __restrict__ out) {
  __shared__ float red[4];
  const int t = threadIdx.x;
  const int widx = t >> 6, lane = t & 63;
  const int m0 = blockIdx.y * 64, c0 = blockIdx.x * 64;
  const int wm = widx & 1, wn = widx >> 1;  // wave pos in 2x2
  const int lm = lane & 15, kg = lane >> 4;

  // ---- epilogue inputs: issue FIRST (pinned at kt==2) ----
  // C/D layout (m89): col = lane&15, row = (lane>>4)*4 + reg
  int evv[16];   // [mt*4+j][nt]: events[r][c], 64B/quarter-wave segments
  float grv[8];
#pragma unroll
  for (int mt = 0; mt < 2; ++mt)
#pragma unroll
    for (int j = 0; j < 4; ++j) {
      const int r = m0 + wm * 32 + mt * 16 + kg * 4 + j;
      grv[mt * 4 + j] = gamma_rows[r];
#pragma unroll
      for (int nt = 0; nt < 2; ++nt)
        evv[(mt * 4 + j) * 2 + nt] =
            events[(size_t)r * C_DIM + c0 + wn * 32 + nt * 16 + lm];
    }
  float gcv[2], nzv[2], cf[2][4];
#pragma unroll
  for (int nt = 0; nt < 2; ++nt) {
    const int c = c0 + wn * 32 + nt * 16 + lm;
    gcv[nt] = gamma_cols[c];
    nzv[nt] = nzc[c];
    const float tt = col_times[c];
    cf[nt][0] = 1.0f; cf[nt][1] = tt; cf[nt][2] = tt * tt * 0.5f;
    cf[nt][3] = cf[nt][2] * tt * (1.0f / 3.0f);
  }

  // fragment base pointers (A layout: lane holds A[m=lm][k=kg*8+j])
  const float* zra = z_rows + (size_t)(m0 + wm * 32 + lm) * D_DIM;
  const float* zcb = z_cols + (size_t)(c0 + wn * 32 + lm) * D_DIM;

  floatx4 acc[2][2];
#pragma unroll
  for (int i = 0; i < 2; ++i)
#pragma unroll
    for (int j = 0; j < 2; ++j) acc[i][j] = (floatx4){0.f, 0.f, 0.f, 0.f};

  // K-loop: 8 inline-converted k-tiles (k = o*64 + d)
#pragma unroll
  for (int kt = 0; kt < 8; ++kt) {
    const int o = kt >> 1;
    const int dk = (kt & 1) * 32 + kg * 8;
    short8 af[2], bf[2];
#pragma unroll
    for (int mt = 0; mt < 2; ++mt) {
      const float* p = zra + (size_t)o * R_DIM * D_DIM + mt * 16 * D_DIM + dk;
      af[mt] = pack8(*(const float4*)p, *(const float4*)(p + 4));
    }
#pragma unroll
    for (int nt = 0; nt < 2; ++nt) {
      const float* p = zcb + nt * 16 * D_DIM + dk;
      const float s = -2.0f * cf[nt][o];
      bf[nt] = pack8(scale4(s, *(const float4*)p), scale4(s, *(const float4*)(p + 4)));
    }
    acc[0][0] = __builtin_amdgcn_mfma_f32_16x16x32_bf16(af[0], bf[0], acc[0][0], 0, 0, 0);
    acc[0][1] = __builtin_amdgcn_mfma_f32_16x16x32_bf16(af[0], bf[1], acc[0][1], 0, 0, 0);
    acc[1][0] = __builtin_amdgcn_mfma_f32_16x16x32_bf16(af[1], bf[0], acc[1][0], 0, 0, 0);
    acc[1][1] = __builtin_amdgcn_mfma_f32_16x16x32_bf16(af[1], bf[1], acc[1][1], 0, 0, 0);
    if (kt == 2) {
      // pin epilogue inputs: loads issued early, completed by now, not sinkable
      asm volatile("" ::"v"(evv[0]), "v"(evv[1]), "v"(evv[2]), "v"(evv[3]),
                   "v"(evv[4]), "v"(evv[5]), "v"(evv[6]), "v"(evv[7]));
      asm volatile("" ::"v"(evv[8]), "v"(evv[9]), "v"(evv[10]), "v"(evv[11]),
                   "v"(evv[12]), "v"(evv[13]), "v"(evv[14]), "v"(evv[15]));
      asm volatile("" ::"v"(grv[0]), "v"(grv[1]), "v"(grv[2]), "v"(grv[3]),
                   "v"(grv[4]), "v"(grv[5]), "v"(grv[6]), "v"(grv[7]),
                   "v"(gcv[0]), "v"(gcv[1]), "v"(nzv[0]), "v"(nzv[1]));
    }
  }
  // k-tile 8: Gram/coef block (k 256..271 real, 272..287 zero)
  {
    short8 af[2], bf[2];
#pragma unroll
    for (int mt = 0; mt < 2; ++mt)
      af[mt] = (kg < 2)
                   ? *(const short8*)(Ag + (size_t)(m0 + wm * 32 + mt * 16 + lm) * 16 + kg * 8)
                   : (short8)0;
#pragma unroll
    for (int nt = 0; nt < 2; ++nt)
      bf[nt] = (kg < 2)
                   ? *(const short8*)(Bg + (size_t)(c0 + wn * 32 + nt * 16 + lm) * 16 + kg * 8)
                   : (short8)0;
    acc[0][0] = __builtin_amdgcn_mfma_f32_16x16x32_bf16(af[0], bf[0], acc[0][0], 0, 0, 0);
    acc[0][1] = __builtin_amdgcn_mfma_f32_16x16x32_bf16(af[0], bf[1], acc[0][1], 0, 0, 0);
    acc[1][0] = __builtin_amdgcn_mfma_f32_16x16x32_bf16(af[1], bf[0], acc[1][0], 0, 0, 0);
    acc[1][1] = __builtin_amdgcn_mfma_f32_16x16x32_bf16(af[1], bf[1], acc[1][1], 0, 0, 0);
  }

  // Epilogue: pure-register; loss = softplus(logit) - ev*logit
  float lsum = 0.0f;
#pragma unroll
  for (int nt = 0; nt < 2; ++nt) {
#pragma unroll
    for (int mt = 0; mt < 2; ++mt) {
#pragma unroll
      for (int j = 0; j < 4; ++j) {
        const float evf = (float)evv[(mt * 4 + j) * 2 + nt];
        const float d2 = acc[mt][nt][j] + nzv[nt];
        const float dist = sqrtf(fmaxf(d2, 0.0f));
        const float logit = grv[mt * 4 + j] + gcv[nt] - dist;
        lsum += fmaxf(logit, 0.0f) + __logf(1.0f + __expf(-fabsf(logit))) -
                evf * logit;
      }
    }
  }
#pragma unroll
  for (int off = 32; off > 0; off >>= 1) lsum += __shfl_down(lsum, off);
  if (lane == 0) red[widx] = lsum;
  __syncthreads();
  if (t == 0) atomicAdd(out, red[0] + red[1] + red[2] + red[3]);
}

extern "C" void kernel_launch(void* const* d_in, const int* in_sizes, int n_in,
                              void* d_out, int out_size, void* d_ws, size_t ws_size,
                              hipStream_t stream) {
  const int* events = (const int*)d_in[0];
  const float* col_times = (const float*)d_in[1];
  const float* z_rows = (const float*)d_in[2];
  const float* z_cols = (const float*)d_in[3];
  const float* gamma_rows = (const float*)d_in[4];
  const float* gamma_cols = (const float*)d_in[5];
  float* out = (float*)d_out;

  ushort* Ag = (ushort*)d_ws;               // 2048*16 bf16 Gram
  ushort* Bg = Ag + (size_t)R_DIM * 16;     // 2048*16 bf16 coef products
  float* nzc = (float*)(Bg + (size_t)C_DIM * 16);  // 2048 f32

  hipMemsetAsync(d_out, 0, sizeof(float), stream);  // out poisoned 0xAA each iter
  prep_kernel<<<R_DIM, 64, 0, stream>>>(col_times, z_rows, z_cols, Ag, Bg, nzc);
  dim3 grid(C_DIM / 64, R_DIM / 64);
  pair_kernel<<<grid, 256, 0, stream>>>(events, col_times, z_rows, z_cols,
                                        gamma_rows, gamma_cols, Ag, Bg, nzc,
                                        out);
}

// Round 11
// 97.902 us; speedup vs baseline: 1.1051x; 1.1051x over previous
//
#include <hip/hip_runtime.h>
#include <hip/hip_bf16.h>
#include <math.h>

// Problem constants: R,C,D,ORDER = 2048,2048,64,3; O=4
#define R_DIM 2048
#define C_DIM 2048
#define D_DIM 64
// Factorization: dist^2[r,c] = sum_k A[r,k]*B[c,k] + ||zc||^2 with
//   k in [0,256): A = z_rows[o][r][d], B = -2*coef_o(t_c)*z_cols[c][d]
//   k in [256,272): A = Gram[r] (4x4 row-major), B = coef_o*coef_o' products
//   k in [272,288): zero pad
#define K_TOT 288
#define NBLK 512  // pair grid: 512 blocks x 2 tiles

typedef __attribute__((ext_vector_type(8))) short short8;   // bf16x8 MFMA frag
typedef __attribute__((ext_vector_type(4))) float floatx4;  // fp32x4 acc

__device__ __forceinline__ ushort f2bf(float f) {  // RNE float->bf16
  unsigned u = __float_as_uint(f);
  return (ushort)((u + 0x7FFFu + ((u >> 16) & 1u)) >> 16);
}

// ---------------- prep: Ab/Bb bf16 matrices, nzc, event byte-pack, cnt=0 -----
// (r9's prep — best known; now zeroes the arrival counter instead of out)
__global__ void prep_kernel(const int* __restrict__ events,
                            const float* __restrict__ col_times,
                            const float* __restrict__ z_rows,
                            const float* __restrict__ z_cols,
                            ushort* __restrict__ Ab,
                            ushort* __restrict__ Bb,
                            float* __restrict__ nzc,
                            unsigned char* __restrict__ Wb8,
                            unsigned* __restrict__ cnt) {
  const int b = blockIdx.x;
  const int t = threadIdx.x;
  const int lane = t & 63;

  if (b == 0 && t == 0) cnt[0] = 0u;  // stream order: before pair_kernel

  // ---- events byte-pack: thread t packs cols [t*8,t*8+8) of row b ----
  {
    const int4 e0 = *(const int4*)&events[(size_t)b * C_DIM + t * 8];
    const int4 e1 = *(const int4*)&events[(size_t)b * C_DIM + t * 8 + 4];
    const unsigned byte =
        (unsigned)(e0.x & 1) | ((unsigned)(e0.y & 1) << 1) |
        ((unsigned)(e0.z & 1) << 2) | ((unsigned)(e0.w & 1) << 3) |
        ((unsigned)(e1.x & 1) << 4) | ((unsigned)(e1.y & 1) << 5) |
        ((unsigned)(e1.z & 1) << 6) | ((unsigned)(e1.w & 1) << 7);
    Wb8[(size_t)b * 256 + t] = (unsigned char)byte;
  }

  if (t < 64) {
    // ---- Ab row b ----
    float zv[4];
#pragma unroll
    for (int o = 0; o < 4; ++o) {
      zv[o] = z_rows[(size_t)(o * R_DIM + b) * D_DIM + lane];
      Ab[(size_t)b * K_TOT + o * 64 + lane] = f2bf(zv[o]);
    }
    float g00 = zv[0] * zv[0], g01 = zv[0] * zv[1], g02 = zv[0] * zv[2],
          g03 = zv[0] * zv[3], g11 = zv[1] * zv[1], g12 = zv[1] * zv[2],
          g13 = zv[1] * zv[3], g22 = zv[2] * zv[2], g23 = zv[2] * zv[3],
          g33 = zv[3] * zv[3];
#pragma unroll
    for (int off = 32; off > 0; off >>= 1) {
      g00 += __shfl_xor(g00, off); g01 += __shfl_xor(g01, off);
      g02 += __shfl_xor(g02, off); g03 += __shfl_xor(g03, off);
      g11 += __shfl_xor(g11, off); g12 += __shfl_xor(g12, off);
      g13 += __shfl_xor(g13, off); g22 += __shfl_xor(g22, off);
      g23 += __shfl_xor(g23, off); g33 += __shfl_xor(g33, off);
    }
    if (lane == 0) {
      ushort* e = Ab + (size_t)b * K_TOT + 256;  // symmetric 4x4
      e[0] = f2bf(g00);  e[1] = f2bf(g01);  e[2] = f2bf(g02);  e[3] = f2bf(g03);
      e[4] = f2bf(g01);  e[5] = f2bf(g11);  e[6] = f2bf(g12);  e[7] = f2bf(g13);
      e[8] = f2bf(g02);  e[9] = f2bf(g12);  e[10] = f2bf(g22); e[11] = f2bf(g23);
      e[12] = f2bf(g03); e[13] = f2bf(g13); e[14] = f2bf(g23); e[15] = f2bf(g33);
    }
    if (lane < 16) Ab[(size_t)b * K_TOT + 272 + lane] = 0;  // pad
  } else if (t < 128) {
    // ---- Bb row b + nzc ----
    const float tt = col_times[b];
    float cf[4];
    cf[0] = 1.0f; cf[1] = tt; cf[2] = tt * tt * 0.5f;
    cf[3] = cf[2] * tt * (1.0f / 3.0f);
    const float zc = z_cols[(size_t)b * D_DIM + lane];
#pragma unroll
    for (int o = 0; o < 4; ++o)
      Bb[(size_t)b * K_TOT + o * 64 + lane] = f2bf(-2.0f * cf[o] * zc);
    float q = zc * zc;
#pragma unroll
    for (int off = 32; off > 0; off >>= 1) q += __shfl_xor(q, off);
    if (lane == 0) {
      nzc[b] = q;
      ushort* e = Bb + (size_t)b * K_TOT + 256;
#pragma unroll
      for (int i = 0; i < 16; ++i) e[i] = f2bf(cf[i >> 2] * cf[i & 3]);
    }
    if (lane < 16) Bb[(size_t)b * K_TOT + 272 + lane] = 0;  // pad
  }
}

// ---------------- pair: 2-tile blocks, no same-address atomics ---------------
// grid (16,32) = 512 blocks; each handles tiles (m0, c0) and (m0, c0+64).
// A-fragments loaded once per kt, reused for both tiles (25% fewer loads).
// Block partial -> plain store to parts[bid]; last block reduces (r4 pattern).
__launch_bounds__(256, 2)
__global__ void pair_kernel(const float* __restrict__ gamma_rows,
                            const float* __restrict__ gamma_cols,
                            const ushort* __restrict__ Ab,
                            const ushort* __restrict__ Bb,
                            const float* __restrict__ nzc,
                            const unsigned char* __restrict__ Wb8,
                            unsigned* __restrict__ cnt,
                            float* __restrict__ parts,
                            float* __restrict__ out) {
  __shared__ float red[4];
  __shared__ float flag;
  const int t = threadIdx.x;
  const int widx = t >> 6, lane = t & 63;
  const int m0 = blockIdx.y * 64, c0 = blockIdx.x * 128;
  const int wm = widx & 1, wn = widx >> 1;  // wave pos in 2x2
  const int lm = lane & 15, kg = lane >> 4;

  // ---- epilogue inputs: issue FIRST, pin at kt==2 ----
  // For tile ti, u32 at r*256 + ((c0+ti*64)>>3) + wn*4 covers cols
  // [c0+ti*64+wn*32, +32); bit for col = nt*16+lm.
  unsigned wbits[2][8];
  float grv[8];
#pragma unroll
  for (int mt = 0; mt < 2; ++mt)
#pragma unroll
    for (int j = 0; j < 4; ++j) {
      const int r = m0 + wm * 32 + mt * 16 + kg * 4 + j;
      grv[mt * 4 + j] = gamma_rows[r];
#pragma unroll
      for (int ti = 0; ti < 2; ++ti)
        wbits[ti][mt * 4 + j] = *(const unsigned*)(
            Wb8 + (size_t)r * 256 + ((c0 + ti * 64) >> 3) + wn * 4);
    }
  float gcv[2][2], nzv[2][2];
#pragma unroll
  for (int ti = 0; ti < 2; ++ti)
#pragma unroll
    for (int nt = 0; nt < 2; ++nt) {
      const int c = c0 + ti * 64 + wn * 32 + nt * 16 + lm;
      gcv[ti][nt] = gamma_cols[c];
      nzv[ti][nt] = nzc[c];
    }

  // fragment base pointers; A layout: lane holds A[m=lane&15][k=kg*8+j]
  const ushort* a0p = Ab + (size_t)(m0 + wm * 32 + lm) * K_TOT + kg * 8;
  const ushort* a1p = a0p + 16 * K_TOT;
  const ushort* bp[2][2];
#pragma unroll
  for (int ti = 0; ti < 2; ++ti) {
    bp[ti][0] = Bb + (size_t)(c0 + ti * 64 + wn * 32 + lm) * K_TOT + kg * 8;
    bp[ti][1] = bp[ti][0] + 16 * K_TOT;
  }

  floatx4 acc[2][2][2];  // [ti][mt][nt]
#pragma unroll
  for (int ti = 0; ti < 2; ++ti)
#pragma unroll
    for (int i = 0; i < 2; ++i)
#pragma unroll
      for (int j = 0; j < 2; ++j) acc[ti][i][j] = (floatx4){0.f, 0.f, 0.f, 0.f};

  // software-pipelined K loop (9 k-tiles of 32); A reused across both tiles
  short8 a0 = *(const short8*)(a0p);
  short8 a1 = *(const short8*)(a1p);
  short8 b00 = *(const short8*)(bp[0][0]);
  short8 b01 = *(const short8*)(bp[0][1]);
  short8 b10 = *(const short8*)(bp[1][0]);
  short8 b11 = *(const short8*)(bp[1][1]);
#pragma unroll
  for (int kt = 0; kt < 9; ++kt) {
    short8 na0, na1, nb00, nb01, nb10, nb11;
    if (kt < 8) {
      na0 = *(const short8*)(a0p + (kt + 1) * 32);
      na1 = *(const short8*)(a1p + (kt + 1) * 32);
      nb00 = *(const short8*)(bp[0][0] + (kt + 1) * 32);
      nb01 = *(const short8*)(bp[0][1] + (kt + 1) * 32);
      nb10 = *(const short8*)(bp[1][0] + (kt + 1) * 32);
      nb11 = *(const short8*)(bp[1][1] + (kt + 1) * 32);
    }
    acc[0][0][0] = __builtin_amdgcn_mfma_f32_16x16x32_bf16(a0, b00, acc[0][0][0], 0, 0, 0);
    acc[0][0][1] = __builtin_amdgcn_mfma_f32_16x16x32_bf16(a0, b01, acc[0][0][1], 0, 0, 0);
    acc[0][1][0] = __builtin_amdgcn_mfma_f32_16x16x32_bf16(a1, b00, acc[0][1][0], 0, 0, 0);
    acc[0][1][1] = __builtin_amdgcn_mfma_f32_16x16x32_bf16(a1, b01, acc[0][1][1], 0, 0, 0);
    acc[1][0][0] = __builtin_amdgcn_mfma_f32_16x16x32_bf16(a0, b10, acc[1][0][0], 0, 0, 0);
    acc[1][0][1] = __builtin_amdgcn_mfma_f32_16x16x32_bf16(a0, b11, acc[1][0][1], 0, 0, 0);
    acc[1][1][0] = __builtin_amdgcn_mfma_f32_16x16x32_bf16(a1, b10, acc[1][1][0], 0, 0, 0);
    acc[1][1][1] = __builtin_amdgcn_mfma_f32_16x16x32_bf16(a1, b11, acc[1][1][1], 0, 0, 0);
    if (kt == 2) {
      // pin epilogue inputs (r8 trick, verified necessary)
      asm volatile("" ::"v"(wbits[0][0]), "v"(wbits[0][1]), "v"(wbits[0][2]),
                   "v"(wbits[0][3]), "v"(wbits[0][4]), "v"(wbits[0][5]),
                   "v"(wbits[0][6]), "v"(wbits[0][7]));
      asm volatile("" ::"v"(wbits[1][0]), "v"(wbits[1][1]), "v"(wbits[1][2]),
                   "v"(wbits[1][3]), "v"(wbits[1][4]), "v"(wbits[1][5]),
                   "v"(wbits[1][6]), "v"(wbits[1][7]));
      asm volatile("" ::"v"(grv[0]), "v"(grv[1]), "v"(grv[2]), "v"(grv[3]),
                   "v"(grv[4]), "v"(grv[5]), "v"(grv[6]), "v"(grv[7]));
      asm volatile("" ::"v"(gcv[0][0]), "v"(gcv[0][1]), "v"(gcv[1][0]),
                   "v"(gcv[1][1]), "v"(nzv[0][0]), "v"(nzv[0][1]),
                   "v"(nzv[1][0]), "v"(nzv[1][1]));
    }
    a0 = na0; a1 = na1; b00 = nb00; b01 = nb01; b10 = nb10; b11 = nb11;
  }

  // Epilogue: pure-register; loss = softplus(logit) - ev*logit
  float lsum = 0.0f;
#pragma unroll
  for (int ti = 0; ti < 2; ++ti)
#pragma unroll
    for (int nt = 0; nt < 2; ++nt) {
      const int cbit = nt * 16 + lm;
#pragma unroll
      for (int mt = 0; mt < 2; ++mt) {
#pragma unroll
        for (int j = 0; j < 4; ++j) {
          const float evf = (float)((wbits[ti][mt * 4 + j] >> cbit) & 1u);
          const float d2 = acc[ti][mt][nt][j] + nzv[ti][nt];
          const float dist = sqrtf(fmaxf(d2, 0.0f));
          const float logit = grv[mt * 4 + j] + gcv[ti][nt] - dist;
          lsum += fmaxf(logit, 0.0f) + __logf(1.0f + __expf(-fabsf(logit))) -
                  evf * logit;
        }
      }
    }
#pragma unroll
  for (int off = 32; off > 0; off >>= 1) lsum += __shfl_down(lsum, off);
  if (lane == 0) red[widx] = lsum;
  __syncthreads();

  // ---- block partial -> plain store; last block reduces (no same-addr atomics)
  const int bid = blockIdx.y * gridDim.x + blockIdx.x;
  if (t == 0) {
    parts[bid] = red[0] + red[1] + red[2] + red[3];
    __threadfence();  // order partial before arrival tick
    const unsigned old = atomicAdd(cnt, 1u);
    flag = (old == NBLK - 1) ? 1.0f : 0.0f;
  }
  __syncthreads();
  if (flag != 0.0f) {
    __threadfence();
    float s = 0.0f;
    for (int i = t; i < NBLK; i += 256) s += atomicAdd(&parts[i], 0.0f);  // coherent read
#pragma unroll
    for (int off = 32; off > 0; off >>= 1) s += __shfl_down(s, off);
    if (lane == 0) red[widx] = s;
    __syncthreads();
    if (t == 0) out[0] = red[0] + red[1] + red[2] + red[3];
  }
}

extern "C" void kernel_launch(void* const* d_in, const int* in_sizes, int n_in,
                              void* d_out, int out_size, void* d_ws, size_t ws_size,
                              hipStream_t stream) {
  const int* events = (const int*)d_in[0];
  const float* col_times = (const float*)d_in[1];
  const float* z_rows = (const float*)d_in[2];
  const float* z_cols = (const float*)d_in[3];
  const float* gamma_rows = (const float*)d_in[4];
  const float* gamma_cols = (const float*)d_in[5];
  float* out = (float*)d_out;

  ushort* Ab = (ushort*)d_ws;                          // 2048*288 bf16
  ushort* Bb = Ab + (size_t)R_DIM * K_TOT;             // 2048*288 bf16
  float* nzc = (float*)(Bb + (size_t)C_DIM * K_TOT);   // 2048 f32
  unsigned char* Wb8 = (unsigned char*)(nzc + C_DIM);  // 2048*256 B byte-pack
  unsigned* cnt = (unsigned*)(Wb8 + (size_t)R_DIM * 256);  // arrival counter
  float* parts = (float*)(cnt + 16);                   // 512 block partials

  prep_kernel<<<R_DIM, 256, 0, stream>>>(events, col_times, z_rows, z_cols, Ab,
                                         Bb, nzc, Wb8, cnt);
  dim3 grid(16, 32);
  pair_kernel<<<grid, 256, 0, stream>>>(gamma_rows, gamma_cols, Ab, Bb, nzc,
                                        Wb8, cnt, parts, out);
}

// Round 12
// 95.919 us; speedup vs baseline: 1.1280x; 1.0207x over previous
//
#include <hip/hip_runtime.h>
#include <hip/hip_bf16.h>
#include <math.h>

// Problem constants: R,C,D,ORDER = 2048,2048,64,3; O=4
#define R_DIM 2048
#define C_DIM 2048
#define D_DIM 64
// Factorization: dist^2[r,c] = sum_k A[r,k]*B[c,k] + ||zc||^2 with
//   k in [0,256): A = z_rows[o][r][d], B = -2*coef_o(t_c)*z_cols[c][d]
//   k in [256,272): A = Gram[r] (4x4 row-major), B = coef_o*coef_o' products
//   k in [272,288): zero pad
#define K_TOT 288

typedef __attribute__((ext_vector_type(8))) short short8;   // bf16x8 MFMA frag
typedef __attribute__((ext_vector_type(4))) float floatx4;  // fp32x4 acc

__device__ __forceinline__ ushort f2bf(float f) {  // RNE float->bf16
  unsigned u = __float_as_uint(f);
  return (ushort)((u + 0x7FFFu + ((u >> 16) & 1u)) >> 16);
}

// ---------------- prep: Ab/Bb bf16 matrices, nzc, event byte-pack, out=0 -----
// Event pack: SHUFFLE-FREE. Thread t packs cols [t*8, t*8+8) of row b into
// ONE byte (bit j = col t*8+j). 32B contiguous load per thread, one byte
// store (block = dense 256B). LE byte order => u32 word w of row r covers
// cols 32w..32w+31, bit c&31.
__global__ void prep_kernel(const int* __restrict__ events,
                            const float* __restrict__ col_times,
                            const float* __restrict__ z_rows,
                            const float* __restrict__ z_cols,
                            ushort* __restrict__ Ab,
                            ushort* __restrict__ Bb,
                            float* __restrict__ nzc,
                            unsigned char* __restrict__ Wb8,
                            float* __restrict__ out) {
  const int b = blockIdx.x;
  const int t = threadIdx.x;
  const int lane = t & 63;

  if (b == 0 && t == 0) out[0] = 0.0f;  // stream order: before pair_kernel

  // ---- events byte-pack: no cross-lane ops, no dependent chains ----
  {
    const int4 e0 = *(const int4*)&events[(size_t)b * C_DIM + t * 8];
    const int4 e1 = *(const int4*)&events[(size_t)b * C_DIM + t * 8 + 4];
    const unsigned byte =
        (unsigned)(e0.x & 1) | ((unsigned)(e0.y & 1) << 1) |
        ((unsigned)(e0.z & 1) << 2) | ((unsigned)(e0.w & 1) << 3) |
        ((unsigned)(e1.x & 1) << 4) | ((unsigned)(e1.y & 1) << 5) |
        ((unsigned)(e1.z & 1) << 6) | ((unsigned)(e1.w & 1) << 7);
    Wb8[(size_t)b * 256 + t] = (unsigned char)byte;
  }

  if (t < 64) {
    // ---- Ab row b ----
    float zv[4];
#pragma unroll
    for (int o = 0; o < 4; ++o) {
      zv[o] = z_rows[(size_t)(o * R_DIM + b) * D_DIM + lane];
      Ab[(size_t)b * K_TOT + o * 64 + lane] = f2bf(zv[o]);
    }
    float g00 = zv[0] * zv[0], g01 = zv[0] * zv[1], g02 = zv[0] * zv[2],
          g03 = zv[0] * zv[3], g11 = zv[1] * zv[1], g12 = zv[1] * zv[2],
          g13 = zv[1] * zv[3], g22 = zv[2] * zv[2], g23 = zv[2] * zv[3],
          g33 = zv[3] * zv[3];
#pragma unroll
    for (int off = 32; off > 0; off >>= 1) {
      g00 += __shfl_xor(g00, off); g01 += __shfl_xor(g01, off);
      g02 += __shfl_xor(g02, off); g03 += __shfl_xor(g03, off);
      g11 += __shfl_xor(g11, off); g12 += __shfl_xor(g12, off);
      g13 += __shfl_xor(g13, off); g22 += __shfl_xor(g22, off);
      g23 += __shfl_xor(g23, off); g33 += __shfl_xor(g33, off);
    }
    if (lane == 0) {
      ushort* e = Ab + (size_t)b * K_TOT + 256;  // symmetric 4x4
      e[0] = f2bf(g00);  e[1] = f2bf(g01);  e[2] = f2bf(g02);  e[3] = f2bf(g03);
      e[4] = f2bf(g01);  e[5] = f2bf(g11);  e[6] = f2bf(g12);  e[7] = f2bf(g13);
      e[8] = f2bf(g02);  e[9] = f2bf(g12);  e[10] = f2bf(g22); e[11] = f2bf(g23);
      e[12] = f2bf(g03); e[13] = f2bf(g13); e[14] = f2bf(g23); e[15] = f2bf(g33);
    }
    if (lane < 16) Ab[(size_t)b * K_TOT + 272 + lane] = 0;  // pad
  } else if (t < 128) {
    // ---- Bb row b + nzc ----
    const float tt = col_times[b];
    float cf[4];
    cf[0] = 1.0f; cf[1] = tt; cf[2] = tt * tt * 0.5f;
    cf[3] = cf[2] * tt * (1.0f / 3.0f);
    const float zc = z_cols[(size_t)b * D_DIM + lane];
#pragma unroll
    for (int o = 0; o < 4; ++o)
      Bb[(size_t)b * K_TOT + o * 64 + lane] = f2bf(-2.0f * cf[o] * zc);
    float q = zc * zc;
#pragma unroll
    for (int off = 32; off > 0; off >>= 1) q += __shfl_xor(q, off);
    if (lane == 0) {
      nzc[b] = q;
      ushort* e = Bb + (size_t)b * K_TOT + 256;
#pragma unroll
      for (int i = 0; i < 16; ++i) e[i] = f2bf(cf[i >> 2] * cf[i & 3]);
    }
    if (lane < 16) Bb[(size_t)b * K_TOT + 272 + lane] = 0;  // pad
  }
}

// ---------------- pair: register-direct MFMA GEMM (r9 best-known) ------------
// 64x64 block tile, 4 waves in 2x2 (32x32/wave), grid 32x32 = 1024 blocks,
// 16 waves/CU. Epilogue inputs issued at kernel start, pinned mid-K-loop.
__launch_bounds__(256, 4)
__global__ void pair_kernel(const float* __restrict__ gamma_rows,
                            const float* __restrict__ gamma_cols,
                            const ushort* __restrict__ Ab,
                            const ushort* __restrict__ Bb,
                            const float* __restrict__ nzc,
                            const unsigned char* __restrict__ Wb8,
                            float* __restrict__ out) {
  __shared__ float red[4];
  const int t = threadIdx.x;
  const int widx = t >> 6, lane = t & 63;
  const int m0 = blockIdx.y * 64, c0 = blockIdx.x * 64;
  const int wm = widx & 1, wn = widx >> 1;  // wave pos in 2x2
  const int lm = lane & 15, kg = lane >> 4;

  // ---- epilogue inputs: issue FIRST, consume at the very end ----
  // u32 at byte offset r*256 + (c0>>3) + wn*4 covers cols [c0+wn*32, +32);
  // bit index for col c is nt*16+lm (LE byte order).
  const size_t wboff = (size_t)(c0 >> 3) + wn * 4;
  unsigned wbits[8];
  float grv[8];
#pragma unroll
  for (int mt = 0; mt < 2; ++mt)
#pragma unroll
    for (int j = 0; j < 4; ++j) {
      const int r = m0 + wm * 32 + mt * 16 + kg * 4 + j;
      wbits[mt * 4 + j] = *(const unsigned*)(Wb8 + (size_t)r * 256 + wboff);
      grv[mt * 4 + j] = gamma_rows[r];
    }
  float gcv[2], nzv[2];
#pragma unroll
  for (int nt = 0; nt < 2; ++nt) {
    const int c = c0 + wn * 32 + nt * 16 + lm;
    gcv[nt] = gamma_cols[c];
    nzv[nt] = nzc[c];
  }

  // lane base pointers; A-operand layout: lane holds A[m=lane&15][k=kg*8+j]
  const ushort* a0p = Ab + (size_t)(m0 + wm * 32 + lm) * K_TOT + kg * 8;
  const ushort* a1p = a0p + 16 * K_TOT;
  const ushort* b0p = Bb + (size_t)(c0 + wn * 32 + lm) * K_TOT + kg * 8;
  const ushort* b1p = b0p + 16 * K_TOT;

  floatx4 acc[2][2];
#pragma unroll
  for (int i = 0; i < 2; ++i)
#pragma unroll
    for (int j = 0; j < 2; ++j) acc[i][j] = (floatx4){0.f, 0.f, 0.f, 0.f};

  // software-pipelined K loop (9 k-tiles of 32)
  short8 a0 = *(const short8*)(a0p);
  short8 a1 = *(const short8*)(a1p);
  short8 b0 = *(const short8*)(b0p);
  short8 b1 = *(const short8*)(b1p);
#pragma unroll
  for (int kt = 0; kt < 9; ++kt) {
    short8 na0, na1, nb0, nb1;
    if (kt < 8) {
      na0 = *(const short8*)(a0p + (kt + 1) * 32);
      na1 = *(const short8*)(a1p + (kt + 1) * 32);
      nb0 = *(const short8*)(b0p + (kt + 1) * 32);
      nb1 = *(const short8*)(b1p + (kt + 1) * 32);
    }
    acc[0][0] = __builtin_amdgcn_mfma_f32_16x16x32_bf16(a0, b0, acc[0][0], 0, 0, 0);
    acc[0][1] = __builtin_amdgcn_mfma_f32_16x16x32_bf16(a0, b1, acc[0][1], 0, 0, 0);
    acc[1][0] = __builtin_amdgcn_mfma_f32_16x16x32_bf16(a1, b0, acc[1][0], 0, 0, 0);
    acc[1][1] = __builtin_amdgcn_mfma_f32_16x16x32_bf16(a1, b1, acc[1][1], 0, 0, 0);
    if (kt == 2) {
      // pin epilogue inputs: loads issued early, completed by now,
      // cannot be sunk into the epilogue (the r4/r5 latency bug)
      asm volatile("" ::"v"(wbits[0]), "v"(wbits[1]), "v"(wbits[2]),
                   "v"(wbits[3]), "v"(wbits[4]), "v"(wbits[5]), "v"(wbits[6]),
                   "v"(wbits[7]));
      asm volatile("" ::"v"(grv[0]), "v"(grv[1]), "v"(grv[2]), "v"(grv[3]),
                   "v"(grv[4]), "v"(grv[5]), "v"(grv[6]), "v"(grv[7]),
                   "v"(gcv[0]), "v"(gcv[1]), "v"(nzv[0]), "v"(nzv[1]));
    }
    a0 = na0; a1 = na1; b0 = nb0; b1 = nb1;
  }

  // Epilogue: pure-register. C/D layout (m89): col=lane&15, row=(lane>>4)*4+reg
  // loss = softplus(logit) - ev*logit (branchless; ev bit = nt*16+lm of wbits)
  float lsum = 0.0f;
#pragma unroll
  for (int nt = 0; nt < 2; ++nt) {
    const int cbit = nt * 16 + lm;
#pragma unroll
    for (int mt = 0; mt < 2; ++mt) {
#pragma unroll
      for (int j = 0; j < 4; ++j) {
        const float evf = (float)((wbits[mt * 4 + j] >> cbit) & 1u);
        const float d2 = acc[mt][nt][j] + nzv[nt];
        const float dist = sqrtf(fmaxf(d2, 0.0f));
        const float logit = grv[mt * 4 + j] + gcv[nt] - dist;
        lsum += fmaxf(logit, 0.0f) + __logf(1.0f + __expf(-fabsf(logit))) -
                evf * logit;
      }
    }
  }
#pragma unroll
  for (int off = 32; off > 0; off >>= 1) lsum += __shfl_down(lsum, off);
  if (lane == 0) red[widx] = lsum;
  __syncthreads();
  if (t == 0) atomicAdd(out, red[0] + red[1] + red[2] + red[3]);
}

extern "C" void kernel_launch(void* const* d_in, const int* in_sizes, int n_in,
                              void* d_out, int out_size, void* d_ws, size_t ws_size,
                              hipStream_t stream) {
  const int* events = (const int*)d_in[0];
  const float* col_times = (const float*)d_in[1];
  const float* z_rows = (const float*)d_in[2];
  const float* z_cols = (const float*)d_in[3];
  const float* gamma_rows = (const float*)d_in[4];
  const float* gamma_cols = (const float*)d_in[5];
  float* out = (float*)d_out;

  ushort* Ab = (ushort*)d_ws;                         // 2048*288 bf16
  ushort* Bb = Ab + (size_t)R_DIM * K_TOT;            // 2048*288 bf16
  float* nzc = (float*)(Bb + (size_t)C_DIM * K_TOT);  // 2048 f32
  unsigned char* Wb8 = (unsigned char*)(nzc + C_DIM); // 2048*256 B byte-pack

  prep_kernel<<<R_DIM, 256, 0, stream>>>(events, col_times, z_rows, z_cols, Ab,
                                         Bb, nzc, Wb8, out);
  dim3 grid(C_DIM / 64, R_DIM / 64);
  pair_kernel<<<grid, 256, 0, stream>>>(gamma_rows, gamma_cols, Ab, Bb, nzc,
                                        Wb8, out);
}